// Round 1
// baseline (236.725 us; speedup 1.0000x reference)
//
#include <hip/hip_runtime.h>

typedef unsigned short u16;
typedef __bf16 bf16x8_v __attribute__((ext_vector_type(8)));
typedef float f32x4 __attribute__((ext_vector_type(4)));

// ---------- bf16 helpers ----------
__device__ __forceinline__ u16 f2bf(float f) {
    unsigned u = __float_as_uint(f);
    unsigned r = u + 0x7fffu + ((u >> 16) & 1u);   // RNE; inputs finite
    return (u16)(r >> 16);
}
__device__ __forceinline__ float bf2f(u16 h) {
    return __uint_as_float(((unsigned)h) << 16);
}

// async global->LDS, 16B per lane; lds dst = WAVE-UNIFORM base, HW adds lane*16
__device__ __forceinline__ void gll16(const u16* g, u16* l) {
    __builtin_amdgcn_global_load_lds(
        (const __attribute__((address_space(1))) void*)g,
        (__attribute__((address_space(3))) void*)l, 16, 0, 0);
}

#define EXP_SHIFT 12.0f   // fixed-shift softmax: e = exp(score - SHIFT)

// Srow lives in dead space of Sb: rows 0..3 of each batch, cols 1024..1535
// (row-block 0 only ever has cols <128 written/read by scores/pv).
__device__ __forceinline__ float* srow_ptr(u16* Sb, int b, int i) {
    return (float*)((char*)Sb + (size_t)b * 8388608 +
                    ((i >> 9) << 12) + 2048 + ((size_t)(i & 511) << 2));
}

// ---------------- prep: x->bf16, W->Wt3 bf16 transposed, zero Srow ----------
// grid 7169 x 256.
__global__ __launch_bounds__(256) void k_prep(const float* __restrict__ x,
                                              const float* __restrict__ Wq,
                                              const float* __restrict__ Wk,
                                              const float* __restrict__ Wv,
                                              u16* __restrict__ xb,
                                              u16* __restrict__ Wt3,
                                              u16* __restrict__ Sb) {
    __shared__ float tile[32][33];
    const int bid = blockIdx.x, tid = threadIdx.x;
    if (bid < 4096) {                       // x fp32 -> bf16, 8 elem/thread
        int i = (bid * 256 + tid) * 8;
        float4 a = *(const float4*)(x + i);
        float4 bb = *(const float4*)(x + i + 4);
        union { int4 p; u16 h[8]; } o;
        o.h[0] = f2bf(a.x);  o.h[1] = f2bf(a.y);  o.h[2] = f2bf(a.z);  o.h[3] = f2bf(a.w);
        o.h[4] = f2bf(bb.x); o.h[5] = f2bf(bb.y); o.h[6] = f2bf(bb.z); o.h[7] = f2bf(bb.w);
        *(int4*)(xb + i) = o.p;
    } else if (bid < 7168) {                // W transpose x3 -> Wt3
        const int w = bid - 4096;
        const int z = w >> 10, rem = w & 1023;
        const int bx = rem & 31, by = rem >> 5;
        const float* W = (z == 0) ? Wq : (z == 1) ? Wk : Wv;
        u16* Wt = Wt3 + (size_t)z * 1024 * 1024;
        const int tx = tid & 31, ty = tid >> 5;
#pragma unroll
        for (int r = 0; r < 4; ++r)
            tile[ty + r * 8][tx] = W[(by * 32 + ty + r * 8) * 1024 + bx * 32 + tx];
        __syncthreads();
#pragma unroll
        for (int r = 0; r < 4; ++r)
            Wt[(bx * 32 + ty + r * 8) * 1024 + by * 32 + tx] =
                f2bf(tile[tx][ty + r * 8]);
    } else {                                // zero Srow dead-space (32 KB)
        const int chunk = tid >> 7;
        const int t = tid & 127;
#pragma unroll
        for (int c = 0; c < 8; ++c) {
            const int cc = c * 2 + chunk;   // 0..15: b = cc>>2, r = cc&3
            char* p = (char*)Sb + (size_t)(cc >> 2) * 8388608 +
                      ((cc & 3) << 12) + 2048;
            int4 z4 = {0, 0, 0, 0};
            *(int4*)(p + t * 16) = z4;
        }
    }
}

// ---------------- GEMM core: NT, BK=64, XOR-swizzled LDS (scores/pv) --------
// C[m][n] = sum_k A[m][k] * Bnt[n][k]. 4 waves (2x2), tile 128x128, BK=64.
// LDS chunk position p of row r holds global chunk p^(r&7).
__device__ __forceinline__ void gemm_core_nt(const u16* __restrict__ A,
                                             const u16* __restrict__ B,
                                             int lda, int ldb, int kLen,
                                             u16* smem, f32x4 acc[4][4]) {
    u16* As = smem;
    u16* Bs = smem + 128 * 64;
    const int tid = threadIdx.x;
    const int wave = tid >> 6;
    const int lane = tid & 63;
    const int rowA = tid >> 3;
    const int kcs  = (tid & 7) ^ (rowA & 7);
    const int row16 = lane & 15;
    const int quad = lane >> 4;
    const int sw = row16 & 7;
    const int wm = (wave >> 1) * 64;
    const int wn = (wave & 1) * 64;

#pragma unroll
    for (int i = 0; i < 4; ++i)
#pragma unroll
        for (int j = 0; j < 4; ++j) {
            f32x4 z = {0.f, 0.f, 0.f, 0.f};
            acc[i][j] = z;
        }

    const u16* Ag[4]; const u16* Bg[4];
    u16 *AsB[4], *BsB[4];
#pragma unroll
    for (int u = 0; u < 4; ++u) {
        Ag[u] = A + (size_t)(u * 32 + rowA) * lda + kcs * 8;
        Bg[u] = B + (size_t)(u * 32 + rowA) * ldb + kcs * 8;
        AsB[u] = As + (u * 256 + wave * 64) * 8;
        BsB[u] = Bs + (u * 256 + wave * 64) * 8;
    }

    const int ktiles = kLen >> 6;
    for (int kt = 0; kt < ktiles; ++kt) {
        __syncthreads();
#pragma unroll
        for (int u = 0; u < 4; ++u) gll16(Ag[u] + kt * 64, AsB[u]);
#pragma unroll
        for (int u = 0; u < 4; ++u) gll16(Bg[u] + kt * 64, BsB[u]);
        __syncthreads();
#pragma unroll
        for (int h = 0; h < 2; ++h) {
            bf16x8_v af[4], bfv[4];
            const int cp = (h * 4 + quad);
#pragma unroll
            for (int i = 0; i < 4; ++i)
                af[i] = *(const bf16x8_v*)(As + (wm + i * 16 + row16) * 64 +
                                           (cp ^ sw) * 8);
#pragma unroll
            for (int j = 0; j < 4; ++j)
                bfv[j] = *(const bf16x8_v*)(Bs + (wn + j * 16 + row16) * 64 +
                                            (cp ^ sw) * 8);
#pragma unroll
            for (int i = 0; i < 4; ++i)
#pragma unroll
                for (int j = 0; j < 4; ++j)
                    acc[i][j] = __builtin_amdgcn_mfma_f32_16x16x32_bf16(
                        af[i], bfv[j], acc[i][j], 0, 0, 0);
        }
    }
}

// Coalesced bf16 epilogue (row-major): wave 64x64 tile via 4 KB LDS slice.
__device__ __forceinline__ void epi_bf16(const f32x4 acc[4][4], u16* smem,
                                         u16* __restrict__ g, int ldg) {
    const int tid = threadIdx.x;
    const int wave = tid >> 6, lane = tid & 63;
    const int row16 = lane & 15, quad = lane >> 4;
    u16* Ts = smem + wave * 2048;
#pragma unroll
    for (int jh = 0; jh < 2; ++jh) {
#pragma unroll
        for (int i = 0; i < 4; ++i)
#pragma unroll
            for (int jj = 0; jj < 2; ++jj) {
                const int j = jh * 2 + jj;
#pragma unroll
                for (int r = 0; r < 4; ++r)
                    Ts[(i * 16 + quad * 4 + r) * 32 + jj * 16 + row16] =
                        f2bf(acc[i][j][r]);
            }
#pragma unroll
        for (int s = 0; s < 4; ++s) {
            const int row = s * 16 + (lane >> 2);
            int4 val = *(const int4*)(Ts + row * 32 + (lane & 3) * 8);
            *(int4*)(g + (size_t)row * ldg + jh * 32 + (lane & 3) * 8) = val;
        }
    }
}

// V-transposed epilogue: wave 64x64 -> Vt[e][s], 16B runs along s.
__device__ __forceinline__ void epi_vt(const f32x4 acc[4][4], u16* smem,
                                       u16* __restrict__ Vt, int m0w, int n0w) {
    const int tid = threadIdx.x;
    const int wave = tid >> 6, lane = tid & 63;
    const int row16 = lane & 15, quad = lane >> 4;
    const int b = m0w >> 11;
    const int sBase = m0w & 2047;
    u16* Ts = smem + wave * 4608;            // 32 x 72 u16
#pragma unroll
    for (int p = 0; p < 2; ++p) {
#pragma unroll
        for (int i = 0; i < 4; ++i)
#pragma unroll
            for (int jj = 0; jj < 2; ++jj) {
                const int j = p * 2 + jj;
                union { unsigned long long d; u16 h[4]; } o;
#pragma unroll
                for (int r = 0; r < 4; ++r) o.h[r] = f2bf(acc[i][j][r]);
                *(unsigned long long*)(Ts + (jj * 16 + row16) * 72 +
                                       i * 16 + quad * 4) = o.d;
            }
#pragma unroll
        for (int rr = 0; rr < 4; ++rr) {
            const int ln = rr * 8 + (lane >> 3);
            const int ck = lane & 7;
            int4 val = *(const int4*)(Ts + ln * 72 + ck * 8);
            const int n = n0w + p * 32 + ln;
            *(int4*)(Vt + ((size_t)b * 1024 + n) * 2048 + sBase + ck * 8) = val;
        }
    }
}

// ---------------- fused QKV projection: 256x256, BK=32, counted-vmcnt -------
// 8 waves (2M x 4N), wave tile 128x64, acc[8][4]. 4 LDS buffers (128 KB
// dynamic), prefetch distance 3 K-tiles, ONE raw s_barrier + counted
// s_waitcnt vmcnt(8) per K-tile (never a full drain in the main loop).
// LDS XOR-swizzle: slot (row, c) holds global chunk c ^ ((row>>1)&3); realized
// via pre-swizzled per-lane GLOBAL src (global_load_lds dest must be linear)
// and the matching XOR on the ds_read_b128 address.
__global__ __launch_bounds__(512, 2) void k_gemm_proj2(
    const u16* __restrict__ X, const u16* __restrict__ Wt3,
    u16* __restrict__ Qb, u16* __restrict__ Kb, u16* __restrict__ Vt) {
    extern __shared__ u16 lds[];             // 4 bufs x (A 8192 + B 8192) u16
    const int tid = threadIdx.x;
    const int wave = tid >> 6, lane = tid & 63;
    const int row16 = lane & 15, quad = lane >> 4;

    // XCD-aware swizzle (384 % 8 == 0 -> simple form is bijective)
    const int bid = blockIdx.x;
    const int lin = (bid & 7) * 48 + (bid >> 3);
    const int mt = lin / 12, nt = lin - mt * 12;
    const int m0 = mt << 8, n0g = nt << 8;

    const u16* Ag = X + (size_t)m0 * 1024;
    const u16* Bg = Wt3 + (size_t)n0g * 1024;

    // staging: wave w covers rows [w*32, w*32+32); part p covers 16 rows.
    // lane L -> row w*32+p*16+(L>>2), LDS chunk (L&3) = linear lane*16B;
    // global chunk = (L&3) ^ ((row>>1)&3)  (source pre-swizzle).
    const int r0 = wave * 32 + (lane >> 2);
    const int r1 = r0 + 16;
    const int c0 = (lane & 3) ^ ((r0 >> 1) & 3);
    const int c1 = (lane & 3) ^ ((r1 >> 1) & 3);
    const u16* gA0 = Ag + (size_t)r0 * 1024 + c0 * 8;
    const u16* gA1 = Ag + (size_t)r1 * 1024 + c1 * 8;
    const u16* gB0 = Bg + (size_t)r0 * 1024 + c0 * 8;
    const u16* gB1 = Bg + (size_t)r1 * 1024 + c1 * 8;
    u16* ldsA0 = lds + (wave * 2 + 0) * 512;
    u16* ldsA1 = lds + (wave * 2 + 1) * 512;
    u16* ldsB0 = ldsA0 + 8192;
    u16* ldsB1 = ldsA1 + 8192;

#define STAGE_A(t_) do { const int b_ = ((t_) & 3) * 16384, k_ = (t_) * 32; \
        gll16(gA0 + k_, ldsA0 + b_); gll16(gA1 + k_, ldsA1 + b_); } while (0)
#define STAGE_B(t_) do { const int b_ = ((t_) & 3) * 16384, k_ = (t_) * 32; \
        gll16(gB0 + k_, ldsB0 + b_); gll16(gB1 + k_, ldsB1 + b_); } while (0)

    const int wm = (wave >> 2) * 128, wn = (wave & 3) * 64;
    // read row = 16*frag + row16 (frag base mult of 16) -> swizzle key is
    // (row16>>1)&3 for every fragment; chunk wanted = quad.
    const int sw8 = (quad ^ ((row16 >> 1) & 3)) << 3;
    int offA[8], offB[4];
#pragma unroll
    for (int i = 0; i < 8; ++i) offA[i] = (wm + i * 16 + row16) * 32 + sw8;
#pragma unroll
    for (int j = 0; j < 4; ++j) offB[j] = (wn + j * 16 + row16) * 32 + sw8 + 8192;

    f32x4 acc[8][4];
#pragma unroll
    for (int i = 0; i < 8; ++i)
#pragma unroll
        for (int j = 0; j < 4; ++j) { f32x4 z = {0.f, 0.f, 0.f, 0.f}; acc[i][j] = z; }

    const int ktiles = 32;                   // K = 1024, BK = 32
    STAGE_A(0); STAGE_B(0);
    STAGE_A(1); STAGE_B(1);
    STAGE_A(2); STAGE_B(2);                  // 12 loads/thread in flight

    for (int t = 0; t < ktiles; ++t) {
        // in-order vmcnt retirement: leaving N=4*min(2, ktiles-1-t) outstanding
        // guarantees tile t's 4 loads (oldest) have landed.
        if (t <= ktiles - 3)
            asm volatile("s_waitcnt vmcnt(8)" ::: "memory");
        else if (t == ktiles - 2)
            asm volatile("s_waitcnt vmcnt(4)" ::: "memory");
        else
            asm volatile("s_waitcnt vmcnt(0)" ::: "memory");
        asm volatile("s_barrier" ::: "memory");

        const u16* buf = lds + (t & 3) * 16384;
        bf16x8_v bq[4], aq[4];
#pragma unroll
        for (int j = 0; j < 4; ++j) bq[j] = *(const bf16x8_v*)(buf + offB[j]);
#pragma unroll
        for (int i = 0; i < 4; ++i) aq[i] = *(const bf16x8_v*)(buf + offA[i]);
        if (t + 3 < ktiles) STAGE_A(t + 3);  // targets buf[(t+3)&3] = tile t-1's, consumed
        __builtin_amdgcn_s_setprio(1);
#pragma unroll
        for (int i = 0; i < 4; ++i)
#pragma unroll
            for (int j = 0; j < 4; ++j)
                acc[i][j] = __builtin_amdgcn_mfma_f32_16x16x32_bf16(
                    aq[i], bq[j], acc[i][j], 0, 0, 0);
        __builtin_amdgcn_s_setprio(0);
#pragma unroll
        for (int i = 0; i < 4; ++i) aq[i] = *(const bf16x8_v*)(buf + offA[4 + i]);
        if (t + 3 < ktiles) STAGE_B(t + 3);
        __builtin_amdgcn_s_setprio(1);
#pragma unroll
        for (int i = 0; i < 4; ++i)
#pragma unroll
            for (int j = 0; j < 4; ++j)
                acc[4 + i][j] = __builtin_amdgcn_mfma_f32_16x16x32_bf16(
                    aq[i], bq[j], acc[4 + i][j], 0, 0, 0);
        __builtin_amdgcn_s_setprio(0);
    }
#undef STAGE_A
#undef STAGE_B

    asm volatile("s_waitcnt lgkmcnt(0)" ::: "memory");
    asm volatile("s_barrier" ::: "memory");  // LDS now reusable by epilogues

    if (n0g < 2048) {
        u16* Y = (n0g < 1024) ? Qb : Kb;
        const int n0 = n0g & 1023;
#pragma unroll
        for (int hf = 0; hf < 2; ++hf)
            epi_bf16(acc + hf * 4, lds,
                     Y + (size_t)(m0 + wm + hf * 64) * 1024 + n0 + wn, 1024);
    } else {
#pragma unroll
        for (int hf = 0; hf < 2; ++hf)
            epi_vt(acc + hf * 4, lds, Vt, m0 + wm + hf * 64, (n0g - 2048) + wn);
    }
}

// Scores + fused unnormalized exp; lower-triangular tiles; grid (136, B).
// Row sums atomicAdd into Srow (dead space inside Sb).
__global__ __launch_bounds__(256, 4) void k_gemm_scores(const u16* __restrict__ Q,
                                                        const u16* __restrict__ Kb,
                                                        u16* __restrict__ Sb) {
    __shared__ u16 smem[16384];
    int t = blockIdx.x, b = blockIdx.y;
    int mt = 0;
    while ((mt + 1) * (mt + 2) / 2 <= t) ++mt;
    int nt = t - mt * (mt + 1) / 2;
    const u16* Qp = Q + (size_t)b * 2048 * 1024 + (size_t)mt * 128 * 1024;
    const u16* Kp = Kb + (size_t)b * 2048 * 1024 + (size_t)nt * 128 * 1024;
    u16* Sp = Sb + (size_t)b * 2048 * 2048;
    f32x4 acc[4][4];
    gemm_core_nt(Qp, Kp, 1024, 1024, 1024, smem, acc);
    const int tid = threadIdx.x, wave = tid >> 6, lane = tid & 63;
    const int wm = (wave >> 1) * 64, wn = (wave & 1) * 64;
    const int row16 = lane & 15, quad = lane >> 4;
    const int mBase = mt * 128 + wm;
    const int nBase = nt * 128 + wn;
    u16* Ts = smem + wave * 2048;
    float rs[4][4];
#pragma unroll
    for (int i = 0; i < 4; ++i)
#pragma unroll
        for (int r = 0; r < 4; ++r) rs[i][r] = 0.f;

    __syncthreads();
#pragma unroll
    for (int jh = 0; jh < 2; ++jh) {
#pragma unroll
        for (int i = 0; i < 4; ++i)
#pragma unroll
            for (int jj = 0; jj < 2; ++jj) {
                const int j = jh * 2 + jj;
                const int n = nBase + jh * 32 + jj * 16 + row16;
#pragma unroll
                for (int r = 0; r < 4; ++r) {
                    const int m = mBase + i * 16 + quad * 4 + r;
                    float e = 0.f;
                    if (n <= m)
                        e = __expf(acc[i][j][r] * 0.03125f - EXP_SHIFT);
                    rs[i][r] += e;
                    Ts[(i * 16 + quad * 4 + r) * 32 + jj * 16 + row16] = f2bf(e);
                }
            }
#pragma unroll
        for (int s = 0; s < 4; ++s) {
            const int row = s * 16 + (lane >> 2);
            int4 val = *(const int4*)(Ts + row * 32 + (lane & 3) * 8);
            *(int4*)(Sp + (size_t)(mBase + row) * 2048 +
                     nBase + jh * 32 + (lane & 3) * 8) = val;
        }
    }
#pragma unroll
    for (int i = 0; i < 4; ++i)
#pragma unroll
        for (int r = 0; r < 4; ++r) {
            float s = rs[i][r];
#pragma unroll
            for (int off = 1; off < 16; off <<= 1) s += __shfl_xor(s, off);
            if (row16 == 0)
                atomicAdd(srow_ptr((u16*)Sb, b, mBase + i * 16 + quad * 4 + r), s);
        }
}

// PV simple: O = (1/Srow) * P'.V; k-extent (mt+1)*128.
// grid (8 nt, 16, B); longest-K first (mt reversed) to shrink the tail.
__global__ __launch_bounds__(256, 4) void k_gemm_pv(u16* __restrict__ P,
                                                    const u16* __restrict__ Vt,
                                                    float* __restrict__ O) {
    __shared__ u16 smem[16384];
    const int nt = blockIdx.x, mt = 15 - blockIdx.y, b = blockIdx.z;
    const u16* Pp = P + (size_t)b * 2048 * 2048 + (size_t)mt * 128 * 2048;
    const u16* Vp = Vt + (size_t)b * 1024 * 2048 + (size_t)nt * 128 * 2048;
    f32x4 acc[4][4];
    gemm_core_nt(Pp, Vp, 2048, 2048, (mt + 1) * 128, smem, acc);
    float* Op = O + (size_t)b * 2048 * 1024;
    const int tid = threadIdx.x, wave = tid >> 6, lane = tid & 63;
    const int wm = (wave >> 1) * 64, wn = (wave & 1) * 64;
    const int row16 = lane & 15, quad = lane >> 4;
    float inv[4][4];
#pragma unroll
    for (int i = 0; i < 4; ++i)
#pragma unroll
        for (int r = 0; r < 4; ++r)
            inv[i][r] = 1.0f / *srow_ptr(P, b, mt * 128 + wm + i * 16 + quad * 4 + r);
#pragma unroll
    for (int i = 0; i < 4; ++i)
#pragma unroll
        for (int j = 0; j < 4; ++j) {
            int m = mt * 128 + wm + i * 16 + quad * 4;
            int n = nt * 128 + wn + j * 16 + row16;
#pragma unroll
            for (int r = 0; r < 4; ++r)
                Op[(size_t)(m + r) * 1024 + n] = acc[i][j][r] * inv[i][r];
        }
}

// ---------------- launcher ----------------
extern "C" void kernel_launch(void* const* d_in, const int* in_sizes, int n_in,
                              void* d_out, int out_size, void* d_ws, size_t ws_size,
                              hipStream_t stream) {
    const float* x  = (const float*)d_in[0];
    const float* Wq = (const float*)d_in[1];
    const float* Wk = (const float*)d_in[2];
    const float* Wv = (const float*)d_in[3];
    float* out = (float*)d_out;
    char* ws = (char*)d_ws;

    u16* xb  = (u16*)(ws);                          // 16 MB: x bf16 [8192,1024]
    u16* Wt3 = (u16*)(ws + (16u << 20));            //  6 MB
    u16* Qb  = (u16*)(ws + (22u << 20));            // 16 MB
    u16* Kb  = (u16*)(ws + (38u << 20));            // 16 MB
    u16* Vt  = (u16*)(ws + (54u << 20));            // 16 MB: V^T [B,1024,2048]
    u16* Sb  = (u16*)(ws + (70u << 20));            // 32 MB: P' (+Srow dead space)

    static bool s_attr_done = false;
    if (!s_attr_done) {                             // allow 128 KB dynamic LDS
        hipFuncSetAttribute(reinterpret_cast<const void*>(k_gemm_proj2),
                            hipFuncAttributeMaxDynamicSharedMemorySize, 131072);
        s_attr_done = true;
    }

    k_prep<<<7169, 256, 0, stream>>>(x, Wq, Wk, Wv, xb, Wt3, Sb);
    k_gemm_proj2<<<dim3(384), dim3(512), 131072, stream>>>(xb, Wt3, Qb, Kb, Vt);
    k_gemm_scores<<<dim3(136, 4), 256, 0, stream>>>(Qb, Kb, Sb);
    k_gemm_pv<<<dim3(8, 16, 4), 256, 0, stream>>>(Sb, Vt, out);
}

// Round 2
// 234.936 us; speedup vs baseline: 1.0076x; 1.0076x over previous
//
#include <hip/hip_runtime.h>

typedef unsigned short u16;
typedef __bf16 bf16x8_v __attribute__((ext_vector_type(8)));
typedef float f32x4 __attribute__((ext_vector_type(4)));

// ---------- bf16 helpers ----------
__device__ __forceinline__ u16 f2bf(float f) {
    unsigned u = __float_as_uint(f);
    unsigned r = u + 0x7fffu + ((u >> 16) & 1u);   // RNE; inputs finite
    return (u16)(r >> 16);
}
__device__ __forceinline__ float bf2f(u16 h) {
    return __uint_as_float(((unsigned)h) << 16);
}

// async global->LDS, 16B per lane; lds dst = WAVE-UNIFORM base, HW adds lane*16
__device__ __forceinline__ void gll16(const u16* g, u16* l) {
    __builtin_amdgcn_global_load_lds(
        (const __attribute__((address_space(1))) void*)g,
        (__attribute__((address_space(3))) void*)l, 16, 0, 0);
}

#define EXP_SHIFT 12.0f   // fixed-shift softmax: e = exp(score - SHIFT)

// Srow lives in dead space of Sb: rows 0..3 of each batch, cols 1024..1535
// (row-block 0 only ever has cols <128 written/read by scores/pv).
__device__ __forceinline__ float* srow_ptr(u16* Sb, int b, int i) {
    return (float*)((char*)Sb + (size_t)b * 8388608 +
                    ((i >> 9) << 12) + 2048 + ((size_t)(i & 511) << 2));
}

// ---------------- prep: x->bf16, W->Wt3 bf16 transposed, zero Srow ----------
// grid 7169 x 256.
__global__ __launch_bounds__(256) void k_prep(const float* __restrict__ x,
                                              const float* __restrict__ Wq,
                                              const float* __restrict__ Wk,
                                              const float* __restrict__ Wv,
                                              u16* __restrict__ xb,
                                              u16* __restrict__ Wt3,
                                              u16* __restrict__ Sb) {
    __shared__ float tile[32][33];
    const int bid = blockIdx.x, tid = threadIdx.x;
    if (bid < 4096) {                       // x fp32 -> bf16, 8 elem/thread
        int i = (bid * 256 + tid) * 8;
        float4 a = *(const float4*)(x + i);
        float4 bb = *(const float4*)(x + i + 4);
        union { int4 p; u16 h[8]; } o;
        o.h[0] = f2bf(a.x);  o.h[1] = f2bf(a.y);  o.h[2] = f2bf(a.z);  o.h[3] = f2bf(a.w);
        o.h[4] = f2bf(bb.x); o.h[5] = f2bf(bb.y); o.h[6] = f2bf(bb.z); o.h[7] = f2bf(bb.w);
        *(int4*)(xb + i) = o.p;
    } else if (bid < 7168) {                // W transpose x3 -> Wt3
        const int w = bid - 4096;
        const int z = w >> 10, rem = w & 1023;
        const int bx = rem & 31, by = rem >> 5;
        const float* W = (z == 0) ? Wq : (z == 1) ? Wk : Wv;
        u16* Wt = Wt3 + (size_t)z * 1024 * 1024;
        const int tx = tid & 31, ty = tid >> 5;
#pragma unroll
        for (int r = 0; r < 4; ++r)
            tile[ty + r * 8][tx] = W[(by * 32 + ty + r * 8) * 1024 + bx * 32 + tx];
        __syncthreads();
#pragma unroll
        for (int r = 0; r < 4; ++r)
            Wt[(bx * 32 + ty + r * 8) * 1024 + by * 32 + tx] =
                f2bf(tile[tx][ty + r * 8]);
    } else {                                // zero Srow dead-space (32 KB)
        const int chunk = tid >> 7;
        const int t = tid & 127;
#pragma unroll
        for (int c = 0; c < 8; ++c) {
            const int cc = c * 2 + chunk;   // 0..15: b = cc>>2, r = cc&3
            char* p = (char*)Sb + (size_t)(cc >> 2) * 8388608 +
                      ((cc & 3) << 12) + 2048;
            int4 z4 = {0, 0, 0, 0};
            *(int4*)(p + t * 16) = z4;
        }
    }
}

// ---------------- GEMM core: NT, BK=64, XOR-swizzled LDS (scores/pv) --------
// C[m][n] = sum_k A[m][k] * Bnt[n][k]. 4 waves (2x2), tile 128x128, BK=64.
// LDS chunk position p of row r holds global chunk p^(r&7).
__device__ __forceinline__ void gemm_core_nt(const u16* __restrict__ A,
                                             const u16* __restrict__ B,
                                             int lda, int ldb, int kLen,
                                             u16* smem, f32x4 acc[4][4]) {
    u16* As = smem;
    u16* Bs = smem + 128 * 64;
    const int tid = threadIdx.x;
    const int wave = tid >> 6;
    const int lane = tid & 63;
    const int rowA = tid >> 3;
    const int kcs  = (tid & 7) ^ (rowA & 7);
    const int row16 = lane & 15;
    const int quad = lane >> 4;
    const int sw = row16 & 7;
    const int wm = (wave >> 1) * 64;
    const int wn = (wave & 1) * 64;

#pragma unroll
    for (int i = 0; i < 4; ++i)
#pragma unroll
        for (int j = 0; j < 4; ++j) {
            f32x4 z = {0.f, 0.f, 0.f, 0.f};
            acc[i][j] = z;
        }

    const u16* Ag[4]; const u16* Bg[4];
    u16 *AsB[4], *BsB[4];
#pragma unroll
    for (int u = 0; u < 4; ++u) {
        Ag[u] = A + (size_t)(u * 32 + rowA) * lda + kcs * 8;
        Bg[u] = B + (size_t)(u * 32 + rowA) * ldb + kcs * 8;
        AsB[u] = As + (u * 256 + wave * 64) * 8;
        BsB[u] = Bs + (u * 256 + wave * 64) * 8;
    }

    const int ktiles = kLen >> 6;
    for (int kt = 0; kt < ktiles; ++kt) {
        __syncthreads();
#pragma unroll
        for (int u = 0; u < 4; ++u) gll16(Ag[u] + kt * 64, AsB[u]);
#pragma unroll
        for (int u = 0; u < 4; ++u) gll16(Bg[u] + kt * 64, BsB[u]);
        __syncthreads();
#pragma unroll
        for (int h = 0; h < 2; ++h) {
            bf16x8_v af[4], bfv[4];
            const int cp = (h * 4 + quad);
#pragma unroll
            for (int i = 0; i < 4; ++i)
                af[i] = *(const bf16x8_v*)(As + (wm + i * 16 + row16) * 64 +
                                           (cp ^ sw) * 8);
#pragma unroll
            for (int j = 0; j < 4; ++j)
                bfv[j] = *(const bf16x8_v*)(Bs + (wn + j * 16 + row16) * 64 +
                                            (cp ^ sw) * 8);
#pragma unroll
            for (int i = 0; i < 4; ++i)
#pragma unroll
                for (int j = 0; j < 4; ++j)
                    acc[i][j] = __builtin_amdgcn_mfma_f32_16x16x32_bf16(
                        af[i], bfv[j], acc[i][j], 0, 0, 0);
        }
    }
}

// Coalesced bf16 epilogue (row-major): wave 64x64 tile via 4 KB LDS slice.
__device__ __forceinline__ void epi_bf16(const f32x4 acc[4][4], u16* smem,
                                         u16* __restrict__ g, int ldg) {
    const int tid = threadIdx.x;
    const int wave = tid >> 6, lane = tid & 63;
    const int row16 = lane & 15, quad = lane >> 4;
    u16* Ts = smem + wave * 2048;
#pragma unroll
    for (int jh = 0; jh < 2; ++jh) {
#pragma unroll
        for (int i = 0; i < 4; ++i)
#pragma unroll
            for (int jj = 0; jj < 2; ++jj) {
                const int j = jh * 2 + jj;
#pragma unroll
                for (int r = 0; r < 4; ++r)
                    Ts[(i * 16 + quad * 4 + r) * 32 + jj * 16 + row16] =
                        f2bf(acc[i][j][r]);
            }
#pragma unroll
        for (int s = 0; s < 4; ++s) {
            const int row = s * 16 + (lane >> 2);
            int4 val = *(const int4*)(Ts + row * 32 + (lane & 3) * 8);
            *(int4*)(g + (size_t)row * ldg + jh * 32 + (lane & 3) * 8) = val;
        }
    }
}

// V-transposed epilogue: wave 64x64 -> Vt[e][s], 16B runs along s.
__device__ __forceinline__ void epi_vt(const f32x4 acc[4][4], u16* smem,
                                       u16* __restrict__ Vt, int m0w, int n0w) {
    const int tid = threadIdx.x;
    const int wave = tid >> 6, lane = tid & 63;
    const int row16 = lane & 15, quad = lane >> 4;
    const int b = m0w >> 11;
    const int sBase = m0w & 2047;
    u16* Ts = smem + wave * 4608;            // 32 x 72 u16
#pragma unroll
    for (int p = 0; p < 2; ++p) {
#pragma unroll
        for (int i = 0; i < 4; ++i)
#pragma unroll
            for (int jj = 0; jj < 2; ++jj) {
                const int j = p * 2 + jj;
                union { unsigned long long d; u16 h[4]; } o;
#pragma unroll
                for (int r = 0; r < 4; ++r) o.h[r] = f2bf(acc[i][j][r]);
                *(unsigned long long*)(Ts + (jj * 16 + row16) * 72 +
                                       i * 16 + quad * 4) = o.d;
            }
#pragma unroll
        for (int rr = 0; rr < 4; ++rr) {
            const int ln = rr * 8 + (lane >> 3);
            const int ck = lane & 7;
            int4 val = *(const int4*)(Ts + ln * 72 + ck * 8);
            const int n = n0w + p * 32 + ln;
            *(int4*)(Vt + ((size_t)b * 1024 + n) * 2048 + sBase + ck * 8) = val;
        }
    }
}

// ---------------- fused QKV projection: 256x256, BK=64, 8-phase -------------
// 8 waves (2M x 4N), wave tile 128x64, acc[8][4]. LDS = 2 K-tile buffers
// (A0,B0 = even kt; A1,B1 = odd kt), 128 KB. Per iteration (2 K-tiles):
// 8 phases of {ds_read subtile || stage half-tile (2 gll16) -> barrier ->
// setprio(1) MFMA x16 setprio(0) -> barrier}. Counted s_waitcnt vmcnt(4) at
// phases 4 & 8 only (2 half-tiles always in flight; never drained in loop).
// Stage slots (iter I): ph1,2 -> A(2I+1); ph3,4 -> B(2I+2); ph5,6 -> A(2I+2);
// ph7,8 -> B(2I+3). Each overwrites a region fully consumed in prior phases.
#define BAR  asm volatile("s_barrier" ::: "memory")
#define VMW4 asm volatile("s_waitcnt vmcnt(4)" ::: "memory")
#define VMW0 asm volatile("s_waitcnt vmcnt(0)" ::: "memory")
// stage one half-tile (128 rows) of K-tile KT into LDS base LB (u16 units)
#define STAGE(LB, GP, KT, H) do { \
    gll16((GP) + (size_t)((H) * 128) * 1024 + (KT) * 64, \
          (LB) + ((H) * 128) * 64 + wave * 512); \
    gll16((GP) + (size_t)((H) * 128 + 64) * 1024 + (KT) * 64, \
          (LB) + ((H) * 128 + 64) * 64 + wave * 512); } while (0)
#define LDA_LO(BUF) do { _Pragma("unroll") for (int i = 0; i < 4; ++i) { \
    a0[i] = *(const bf16x8_v*)((BUF) + offA[i]); \
    a1[i] = *(const bf16x8_v*)((BUF) + (offA[i] ^ 32)); } } while (0)
#define LDA_HI(BUF) do { _Pragma("unroll") for (int i = 0; i < 4; ++i) { \
    a0[i] = *(const bf16x8_v*)((BUF) + offA[4 + i]); \
    a1[i] = *(const bf16x8_v*)((BUF) + (offA[4 + i] ^ 32)); } } while (0)
#define LDB_K0(BUF) do { _Pragma("unroll") for (int j = 0; j < 4; ++j) \
    b0[j] = *(const bf16x8_v*)((BUF) + offB[j]); } while (0)
#define LDB_K1(BUF) do { _Pragma("unroll") for (int j = 0; j < 4; ++j) \
    b1[j] = *(const bf16x8_v*)((BUF) + (offB[j] ^ 32)); } while (0)
#define MFMA16(IOFF, AA, BB) do { __builtin_amdgcn_s_setprio(1); \
    _Pragma("unroll") for (int i = 0; i < 4; ++i) \
    _Pragma("unroll") for (int j = 0; j < 4; ++j) \
        acc[(IOFF) + i][j] = __builtin_amdgcn_mfma_f32_16x16x32_bf16( \
            AA[i], BB[j], acc[(IOFF) + i][j], 0, 0, 0); \
    __builtin_amdgcn_s_setprio(0); } while (0)

__global__ __launch_bounds__(512, 2) void k_gemm_proj2(
    const u16* __restrict__ X, const u16* __restrict__ Wt3,
    u16* __restrict__ Qb, u16* __restrict__ Kb, u16* __restrict__ Vt) {
    extern __shared__ u16 lds[];             // A0 B0 A1 B1, 16384 u16 each
    const int tid = threadIdx.x;
    const int wave = tid >> 6, lane = tid & 63;
    const int row16 = lane & 15, quad = lane >> 4;

    // XCD-aware swizzle (384 % 8 == 0 -> bijective); 12 consecutive lins
    // share one A-panel.
    const int bid = blockIdx.x;
    const int lin = (bid & 7) * 48 + (bid >> 3);
    const int mt = lin / 12, nt = lin - mt * 12;
    const int m0 = mt << 8, n0g = nt << 8;

    // stager: wave covers 8 rows/slab; lane -> row (lane>>3), chunk (lane&7).
    // global chunk = pos ^ (row&7) (inverse of the read swizzle).
    const int rowls = wave * 8 + (lane >> 3);               // 0..63 in slab
    const int chk = ((lane & 7) ^ ((lane >> 3) & 7)) << 3;  // u16 offset
    const u16* gA = X + (size_t)(m0 + rowls) * 1024 + chk;
    const u16* gB = Wt3 + (size_t)(n0g + rowls) * 1024 + chk;

    u16* A0b = lds;
    u16* B0b = lds + 16384;
    u16* A1b = lds + 32768;
    u16* B1b = lds + 49152;

    // reader: frag chunk q (=quad for kk0, quad^4 for kk1) at pos q^(row16&7);
    // kk1 offset = kk0 offset ^ 32 (u16).
    const int wm = (wave >> 2) * 128, wn = (wave & 3) * 64;
    const int csw = (quad ^ (row16 & 7)) << 3;
    int offA[8], offB[4];
#pragma unroll
    for (int i = 0; i < 8; ++i) offA[i] = (wm + i * 16 + row16) * 64 + csw;
#pragma unroll
    for (int j = 0; j < 4; ++j) offB[j] = (wn + j * 16 + row16) * 64 + csw;

    f32x4 acc[8][4];
#pragma unroll
    for (int i = 0; i < 8; ++i)
#pragma unroll
        for (int j = 0; j < 4; ++j) { f32x4 z = {0.f, 0.f, 0.f, 0.f}; acc[i][j] = z; }

    // prologue: tile0 (A,B) + tile1 B = 12 loads; retire tile0 (keep 4 in flight)
    STAGE(A0b, gA, 0, 0); STAGE(A0b, gA, 0, 1);
    STAGE(B0b, gB, 0, 0); STAGE(B0b, gB, 0, 1);
    STAGE(B1b, gB, 1, 0); STAGE(B1b, gB, 1, 1);
    VMW4; BAR;

    bf16x8_v a0[4], a1[4], b0[4], b1[4];

    for (int I = 0; I < 7; ++I) {
        const int kt1 = 2 * I + 1, ktA = 2 * I + 2, ktB = 2 * I + 3;
        // ---- K-tile 2I from buf0 ----
        LDA_LO(A0b); LDB_K0(B0b);                 // ph1: 12 reads
        STAGE(A1b, gA, kt1, 0);
        BAR; MFMA16(0, a0, b0); BAR;
        LDB_K1(B0b);                              // ph2: 4 reads
        STAGE(A1b, gA, kt1, 1);
        BAR; MFMA16(0, a1, b1); BAR;
        LDA_HI(A0b);                              // ph3: 8 reads
        STAGE(B0b, gB, ktA, 0);
        BAR; MFMA16(4, a0, b0); BAR;
        STAGE(B0b, gB, ktA, 1);                   // ph4: 0 reads
        VMW4;                                     // retires A(2I+1) halves
        BAR; MFMA16(4, a1, b1); BAR;
        // ---- K-tile 2I+1 from buf1 ----
        LDA_LO(A1b); LDB_K0(B1b);                 // ph5
        STAGE(A0b, gA, ktA, 0);
        BAR; MFMA16(0, a0, b0); BAR;
        LDB_K1(B1b);                              // ph6
        STAGE(A0b, gA, ktA, 1);
        BAR; MFMA16(0, a1, b1); BAR;
        LDA_HI(A1b);                              // ph7
        STAGE(B1b, gB, ktB, 0);
        BAR; MFMA16(4, a0, b0); BAR;
        STAGE(B1b, gB, ktB, 1);                   // ph8
        VMW4;                                     // retires tile 2I+2 halves
        BAR; MFMA16(4, a1, b1); BAR;
    }
    // ---- tail: I=7 (kt 14 in buf0, kt 15 in buf1); no stages past kt15 ----
    {
        LDA_LO(A0b); LDB_K0(B0b);
        STAGE(A1b, gA, 15, 0);
        BAR; MFMA16(0, a0, b0); BAR;
        LDB_K1(B0b);
        STAGE(A1b, gA, 15, 1);
        BAR; MFMA16(0, a1, b1); BAR;
        LDA_HI(A0b);
        BAR; MFMA16(4, a0, b0); BAR;
        VMW0;                                     // drain: tile15 fully landed
        BAR; MFMA16(4, a1, b1); BAR;
        LDA_LO(A1b); LDB_K0(B1b);
        BAR; MFMA16(0, a0, b0); BAR;
        LDB_K1(B1b);
        BAR; MFMA16(0, a1, b1); BAR;
        LDA_HI(A1b);
        BAR; MFMA16(4, a0, b0); BAR;
        MFMA16(4, a1, b1);
        BAR;                                      // LDS reusable by epilogues
    }

    if (n0g < 2048) {
        u16* Y = (n0g < 1024) ? Qb : Kb;
        const int n0 = n0g & 1023;
#pragma unroll
        for (int hf = 0; hf < 2; ++hf)
            epi_bf16(acc + hf * 4, lds,
                     Y + (size_t)(m0 + wm + hf * 64) * 1024 + n0 + wn, 1024);
    } else {
#pragma unroll
        for (int hf = 0; hf < 2; ++hf)
            epi_vt(acc + hf * 4, lds, Vt, m0 + wm + hf * 64, (n0g - 2048) + wn);
    }
}

// Scores + fused unnormalized exp; lower-triangular tiles; grid (136, B).
// Row sums atomicAdd into Srow (dead space inside Sb).
__global__ __launch_bounds__(256, 4) void k_gemm_scores(const u16* __restrict__ Q,
                                                        const u16* __restrict__ Kb,
                                                        u16* __restrict__ Sb) {
    __shared__ u16 smem[16384];
    int t = blockIdx.x, b = blockIdx.y;
    int mt = 0;
    while ((mt + 1) * (mt + 2) / 2 <= t) ++mt;
    int nt = t - mt * (mt + 1) / 2;
    const u16* Qp = Q + (size_t)b * 2048 * 1024 + (size_t)mt * 128 * 1024;
    const u16* Kp = Kb + (size_t)b * 2048 * 1024 + (size_t)nt * 128 * 1024;
    u16* Sp = Sb + (size_t)b * 2048 * 2048;
    f32x4 acc[4][4];
    gemm_core_nt(Qp, Kp, 1024, 1024, 1024, smem, acc);
    const int tid = threadIdx.x, wave = tid >> 6, lane = tid & 63;
    const int wm = (wave >> 1) * 64, wn = (wave & 1) * 64;
    const int row16 = lane & 15, quad = lane >> 4;
    const int mBase = mt * 128 + wm;
    const int nBase = nt * 128 + wn;
    u16* Ts = smem + wave * 2048;
    float rs[4][4];
#pragma unroll
    for (int i = 0; i < 4; ++i)
#pragma unroll
        for (int r = 0; r < 4; ++r) rs[i][r] = 0.f;

    __syncthreads();
#pragma unroll
    for (int jh = 0; jh < 2; ++jh) {
#pragma unroll
        for (int i = 0; i < 4; ++i)
#pragma unroll
            for (int jj = 0; jj < 2; ++jj) {
                const int j = jh * 2 + jj;
                const int n = nBase + jh * 32 + jj * 16 + row16;
#pragma unroll
                for (int r = 0; r < 4; ++r) {
                    const int m = mBase + i * 16 + quad * 4 + r;
                    float e = 0.f;
                    if (n <= m)
                        e = __expf(acc[i][j][r] * 0.03125f - EXP_SHIFT);
                    rs[i][r] += e;
                    Ts[(i * 16 + quad * 4 + r) * 32 + jj * 16 + row16] = f2bf(e);
                }
            }
#pragma unroll
        for (int s = 0; s < 4; ++s) {
            const int row = s * 16 + (lane >> 2);
            int4 val = *(const int4*)(Ts + row * 32 + (lane & 3) * 8);
            *(int4*)(Sp + (size_t)(mBase + row) * 2048 +
                     nBase + jh * 32 + (lane & 3) * 8) = val;
        }
    }
#pragma unroll
    for (int i = 0; i < 4; ++i)
#pragma unroll
        for (int r = 0; r < 4; ++r) {
            float s = rs[i][r];
#pragma unroll
            for (int off = 1; off < 16; off <<= 1) s += __shfl_xor(s, off);
            if (row16 == 0)
                atomicAdd(srow_ptr((u16*)Sb, b, mBase + i * 16 + quad * 4 + r), s);
        }
}

// PV simple: O = (1/Srow) * P'.V; k-extent (mt+1)*128.
// grid (8 nt, 16, B); longest-K first (mt reversed) to shrink the tail.
__global__ __launch_bounds__(256, 4) void k_gemm_pv(u16* __restrict__ P,
                                                    const u16* __restrict__ Vt,
                                                    float* __restrict__ O) {
    __shared__ u16 smem[16384];
    const int nt = blockIdx.x, mt = 15 - blockIdx.y, b = blockIdx.z;
    const u16* Pp = P + (size_t)b * 2048 * 2048 + (size_t)mt * 128 * 2048;
    const u16* Vp = Vt + (size_t)b * 1024 * 2048 + (size_t)nt * 128 * 2048;
    f32x4 acc[4][4];
    gemm_core_nt(Pp, Vp, 2048, 2048, (mt + 1) * 128, smem, acc);
    float* Op = O + (size_t)b * 2048 * 1024;
    const int tid = threadIdx.x, wave = tid >> 6, lane = tid & 63;
    const int wm = (wave >> 1) * 64, wn = (wave & 1) * 64;
    const int row16 = lane & 15, quad = lane >> 4;
    float inv[4][4];
#pragma unroll
    for (int i = 0; i < 4; ++i)
#pragma unroll
        for (int r = 0; r < 4; ++r)
            inv[i][r] = 1.0f / *srow_ptr(P, b, mt * 128 + wm + i * 16 + quad * 4 + r);
#pragma unroll
    for (int i = 0; i < 4; ++i)
#pragma unroll
        for (int j = 0; j < 4; ++j) {
            int m = mt * 128 + wm + i * 16 + quad * 4;
            int n = nt * 128 + wn + j * 16 + row16;
#pragma unroll
            for (int r = 0; r < 4; ++r)
                Op[(size_t)(m + r) * 1024 + n] = acc[i][j][r] * inv[i][r];
        }
}

// ---------------- launcher ----------------
extern "C" void kernel_launch(void* const* d_in, const int* in_sizes, int n_in,
                              void* d_out, int out_size, void* d_ws, size_t ws_size,
                              hipStream_t stream) {
    const float* x  = (const float*)d_in[0];
    const float* Wq = (const float*)d_in[1];
    const float* Wk = (const float*)d_in[2];
    const float* Wv = (const float*)d_in[3];
    float* out = (float*)d_out;
    char* ws = (char*)d_ws;

    u16* xb  = (u16*)(ws);                          // 16 MB: x bf16 [8192,1024]
    u16* Wt3 = (u16*)(ws + (16u << 20));            //  6 MB
    u16* Qb  = (u16*)(ws + (22u << 20));            // 16 MB
    u16* Kb  = (u16*)(ws + (38u << 20));            // 16 MB
    u16* Vt  = (u16*)(ws + (54u << 20));            // 16 MB: V^T [B,1024,2048]
    u16* Sb  = (u16*)(ws + (70u << 20));            // 32 MB: P' (+Srow dead space)

    static bool s_attr_done = false;
    if (!s_attr_done) {                             // allow 128 KB dynamic LDS
        hipFuncSetAttribute(reinterpret_cast<const void*>(k_gemm_proj2),
                            hipFuncAttributeMaxDynamicSharedMemorySize, 131072);
        s_attr_done = true;
    }

    k_prep<<<7169, 256, 0, stream>>>(x, Wq, Wk, Wv, xb, Wt3, Sb);
    k_gemm_proj2<<<dim3(384), dim3(512), 131072, stream>>>(xb, Wt3, Qb, Kb, Vt);
    k_gemm_scores<<<dim3(136, 4), 256, 0, stream>>>(Qb, Kb, Sb);
    k_gemm_pv<<<dim3(8, 16, 4), 256, 0, stream>>>(Sb, Vt, out);
}

// Round 3
// 209.582 us; speedup vs baseline: 1.1295x; 1.1210x over previous
//
#include <hip/hip_runtime.h>

typedef unsigned short u16;
typedef __bf16 bf16x8_v __attribute__((ext_vector_type(8)));
typedef float f32x4 __attribute__((ext_vector_type(4)));

// ---------- bf16 helpers ----------
__device__ __forceinline__ u16 f2bf(float f) {
    unsigned u = __float_as_uint(f);
    unsigned r = u + 0x7fffu + ((u >> 16) & 1u);   // RNE; inputs finite
    return (u16)(r >> 16);
}
__device__ __forceinline__ float bf2f(u16 h) {
    return __uint_as_float(((unsigned)h) << 16);
}

// async global->LDS, 16B per lane; lds dst = WAVE-UNIFORM base, HW adds lane*16
__device__ __forceinline__ void gll16(const u16* g, u16* l) {
    __builtin_amdgcn_global_load_lds(
        (const __attribute__((address_space(1))) void*)g,
        (__attribute__((address_space(3))) void*)l, 16, 0, 0);
}

#define EXP_SHIFT 12.0f   // fixed-shift softmax: e = exp(score - SHIFT)

// Srow lives in dead space of Sb: rows 0..3 of each batch, cols 1024..1535
// (row-block 0 only ever has cols <128 written/read by scores/pv).
__device__ __forceinline__ float* srow_ptr(u16* Sb, int b, int i) {
    return (float*)((char*)Sb + (size_t)b * 8388608 +
                    ((i >> 9) << 12) + 2048 + ((size_t)(i & 511) << 2));
}

// ---------------- prep: x->bf16, W->Wt3 bf16 transposed, zero Srow ----------
// grid 7169 x 256.
__global__ __launch_bounds__(256) void k_prep(const float* __restrict__ x,
                                              const float* __restrict__ Wq,
                                              const float* __restrict__ Wk,
                                              const float* __restrict__ Wv,
                                              u16* __restrict__ xb,
                                              u16* __restrict__ Wt3,
                                              u16* __restrict__ Sb) {
    __shared__ float tile[32][33];
    const int bid = blockIdx.x, tid = threadIdx.x;
    if (bid < 4096) {                       // x fp32 -> bf16, 8 elem/thread
        int i = (bid * 256 + tid) * 8;
        float4 a = *(const float4*)(x + i);
        float4 bb = *(const float4*)(x + i + 4);
        union { int4 p; u16 h[8]; } o;
        o.h[0] = f2bf(a.x);  o.h[1] = f2bf(a.y);  o.h[2] = f2bf(a.z);  o.h[3] = f2bf(a.w);
        o.h[4] = f2bf(bb.x); o.h[5] = f2bf(bb.y); o.h[6] = f2bf(bb.z); o.h[7] = f2bf(bb.w);
        *(int4*)(xb + i) = o.p;
    } else if (bid < 7168) {                // W transpose x3 -> Wt3
        const int w = bid - 4096;
        const int z = w >> 10, rem = w & 1023;
        const int bx = rem & 31, by = rem >> 5;
        const float* W = (z == 0) ? Wq : (z == 1) ? Wk : Wv;
        u16* Wt = Wt3 + (size_t)z * 1024 * 1024;
        const int tx = tid & 31, ty = tid >> 5;
#pragma unroll
        for (int r = 0; r < 4; ++r)
            tile[ty + r * 8][tx] = W[(by * 32 + ty + r * 8) * 1024 + bx * 32 + tx];
        __syncthreads();
#pragma unroll
        for (int r = 0; r < 4; ++r)
            Wt[(bx * 32 + ty + r * 8) * 1024 + by * 32 + tx] =
                f2bf(tile[tx][ty + r * 8]);
    } else {                                // zero Srow dead-space (32 KB)
        const int chunk = tid >> 7;
        const int t = tid & 127;
#pragma unroll
        for (int c = 0; c < 8; ++c) {
            const int cc = c * 2 + chunk;   // 0..15: b = cc>>2, r = cc&3
            char* p = (char*)Sb + (size_t)(cc >> 2) * 8388608 +
                      ((cc & 3) << 12) + 2048;
            int4 z4 = {0, 0, 0, 0};
            *(int4*)(p + t * 16) = z4;
        }
    }
}

// ---------------- GEMM core: NT, BK=64, XOR-swizzled LDS ----------------
// C[m][n] = sum_k A[m][k] * Bnt[n][k]. 4 waves (2x2), tile 128x128, BK=64.
// LDS chunk position p of row r holds global chunk p^(r&7).
__device__ __forceinline__ void gemm_core_nt(const u16* __restrict__ A,
                                             const u16* __restrict__ B,
                                             int lda, int ldb, int kLen,
                                             u16* smem, f32x4 acc[4][4]) {
    u16* As = smem;
    u16* Bs = smem + 128 * 64;
    const int tid = threadIdx.x;
    const int wave = tid >> 6;
    const int lane = tid & 63;
    const int rowA = tid >> 3;
    const int kcs  = (tid & 7) ^ (rowA & 7);
    const int row16 = lane & 15;
    const int quad = lane >> 4;
    const int sw = row16 & 7;
    const int wm = (wave >> 1) * 64;
    const int wn = (wave & 1) * 64;

#pragma unroll
    for (int i = 0; i < 4; ++i)
#pragma unroll
        for (int j = 0; j < 4; ++j) {
            f32x4 z = {0.f, 0.f, 0.f, 0.f};
            acc[i][j] = z;
        }

    const u16* Ag[4]; const u16* Bg[4];
    u16 *AsB[4], *BsB[4];
#pragma unroll
    for (int u = 0; u < 4; ++u) {
        Ag[u] = A + (size_t)(u * 32 + rowA) * lda + kcs * 8;
        Bg[u] = B + (size_t)(u * 32 + rowA) * ldb + kcs * 8;
        AsB[u] = As + (u * 256 + wave * 64) * 8;
        BsB[u] = Bs + (u * 256 + wave * 64) * 8;
    }

    const int ktiles = kLen >> 6;
    for (int kt = 0; kt < ktiles; ++kt) {
        __syncthreads();
#pragma unroll
        for (int u = 0; u < 4; ++u) gll16(Ag[u] + kt * 64, AsB[u]);
#pragma unroll
        for (int u = 0; u < 4; ++u) gll16(Bg[u] + kt * 64, BsB[u]);
        __syncthreads();
#pragma unroll
        for (int h = 0; h < 2; ++h) {
            bf16x8_v af[4], bfv[4];
            const int cp = (h * 4 + quad);
#pragma unroll
            for (int i = 0; i < 4; ++i)
                af[i] = *(const bf16x8_v*)(As + (wm + i * 16 + row16) * 64 +
                                           (cp ^ sw) * 8);
#pragma unroll
            for (int j = 0; j < 4; ++j)
                bfv[j] = *(const bf16x8_v*)(Bs + (wn + j * 16 + row16) * 64 +
                                            (cp ^ sw) * 8);
#pragma unroll
            for (int i = 0; i < 4; ++i)
#pragma unroll
                for (int j = 0; j < 4; ++j)
                    acc[i][j] = __builtin_amdgcn_mfma_f32_16x16x32_bf16(
                        af[i], bfv[j], acc[i][j], 0, 0, 0);
        }
    }
}

// Coalesced bf16 epilogue (row-major): wave 64x64 tile via 4 KB LDS slice.
__device__ __forceinline__ void epi_bf16(const f32x4 acc[4][4], u16* smem,
                                         u16* __restrict__ g, int ldg) {
    const int tid = threadIdx.x;
    const int wave = tid >> 6, lane = tid & 63;
    const int row16 = lane & 15, quad = lane >> 4;
    u16* Ts = smem + wave * 2048;
#pragma unroll
    for (int jh = 0; jh < 2; ++jh) {
#pragma unroll
        for (int i = 0; i < 4; ++i)
#pragma unroll
            for (int jj = 0; jj < 2; ++jj) {
                const int j = jh * 2 + jj;
#pragma unroll
                for (int r = 0; r < 4; ++r)
                    Ts[(i * 16 + quad * 4 + r) * 32 + jj * 16 + row16] =
                        f2bf(acc[i][j][r]);
            }
#pragma unroll
        for (int s = 0; s < 4; ++s) {
            const int row = s * 16 + (lane >> 2);
            int4 val = *(const int4*)(Ts + row * 32 + (lane & 3) * 8);
            *(int4*)(g + (size_t)row * ldg + jh * 32 + (lane & 3) * 8) = val;
        }
    }
}

// V-transposed epilogue: wave 64x64 -> Vt[e][s], 16B runs along s.
__device__ __forceinline__ void epi_vt(const f32x4 acc[4][4], u16* smem,
                                       u16* __restrict__ Vt, int m0w, int n0w) {
    const int tid = threadIdx.x;
    const int wave = tid >> 6, lane = tid & 63;
    const int row16 = lane & 15, quad = lane >> 4;
    const int b = m0w >> 11;
    const int sBase = m0w & 2047;
    u16* Ts = smem + wave * 4608;            // 32 x 72 u16
#pragma unroll
    for (int p = 0; p < 2; ++p) {
#pragma unroll
        for (int i = 0; i < 4; ++i)
#pragma unroll
            for (int jj = 0; jj < 2; ++jj) {
                const int j = p * 2 + jj;
                union { unsigned long long d; u16 h[4]; } o;
#pragma unroll
                for (int r = 0; r < 4; ++r) o.h[r] = f2bf(acc[i][j][r]);
                *(unsigned long long*)(Ts + (jj * 16 + row16) * 72 +
                                       i * 16 + quad * 4) = o.d;
            }
#pragma unroll
        for (int rr = 0; rr < 4; ++rr) {
            const int ln = rr * 8 + (lane >> 3);
            const int ck = lane & 7;
            int4 val = *(const int4*)(Ts + ln * 72 + ck * 8);
            const int n = n0w + p * 32 + ln;
            *(int4*)(Vt + ((size_t)b * 1024 + n) * 2048 + sBase + ck * 8) = val;
        }
    }
}

// ---------------- fused QKV projection (r0 structure, 128x128, 3 blk/CU) ----
__global__ __launch_bounds__(256, 3) void k_gemm_proj(const u16* __restrict__ X,
                                                      const u16* __restrict__ Wt3,
                                                      u16* __restrict__ Qb,
                                                      u16* __restrict__ Kb,
                                                      u16* __restrict__ Vt) {
    __shared__ u16 smem[18432];              // 36 KB
    const int n0g = blockIdx.x * 128, m0 = blockIdx.y * 128;
    f32x4 acc[4][4];
    gemm_core_nt(X + (size_t)m0 * 1024, Wt3 + (size_t)n0g * 1024, 1024, 1024, 1024,
                 smem, acc);
    const int tid = threadIdx.x, wave = tid >> 6;
    const int wm = (wave >> 1) * 64, wn = (wave & 1) * 64;
    __syncthreads();
    if (n0g < 2048) {
        u16* Y = (n0g < 1024) ? Qb : Kb;
        const int n0 = n0g & 1023;
        epi_bf16(acc, smem, Y + (size_t)(m0 + wm) * 1024 + n0 + wn, 1024);
    } else {
        epi_vt(acc, smem, Vt, m0 + wm, (n0g - 2048) + wn);
    }
}

// Scores + fused unnormalized exp; lower-triangular tiles; grid 544 (1-D).
// XCD-grouping: 68 consecutive triangle indices per XCD (assumes RR bid%8 ->
// XCD); consecutive t share the Q-panel (mt) -> Q stays L2-resident.
__global__ __launch_bounds__(256, 4) void k_gemm_scores(const u16* __restrict__ Q,
                                                        const u16* __restrict__ Kb,
                                                        u16* __restrict__ Sb) {
    __shared__ u16 smem[16384];
    const int lin = blockIdx.x;                       // 0..543
    const int lin2 = (lin & 7) * 68 + (lin >> 3);     // bijective (544 = 8*68)
    int t = lin2 % 136, b = lin2 / 136;
    int mt = 0;
    while ((mt + 1) * (mt + 2) / 2 <= t) ++mt;
    int nt = t - mt * (mt + 1) / 2;
    const u16* Qp = Q + (size_t)b * 2048 * 1024 + (size_t)mt * 128 * 1024;
    const u16* Kp = Kb + (size_t)b * 2048 * 1024 + (size_t)nt * 128 * 1024;
    u16* Sp = Sb + (size_t)b * 2048 * 2048;
    f32x4 acc[4][4];
    gemm_core_nt(Qp, Kp, 1024, 1024, 1024, smem, acc);
    const int tid = threadIdx.x, wave = tid >> 6, lane = tid & 63;
    const int wm = (wave >> 1) * 64, wn = (wave & 1) * 64;
    const int row16 = lane & 15, quad = lane >> 4;
    const int mBase = mt * 128 + wm;
    const int nBase = nt * 128 + wn;
    u16* Ts = smem + wave * 2048;
    float rs[4][4];
#pragma unroll
    for (int i = 0; i < 4; ++i)
#pragma unroll
        for (int r = 0; r < 4; ++r) rs[i][r] = 0.f;

    __syncthreads();
#pragma unroll
    for (int jh = 0; jh < 2; ++jh) {
#pragma unroll
        for (int i = 0; i < 4; ++i)
#pragma unroll
            for (int jj = 0; jj < 2; ++jj) {
                const int j = jh * 2 + jj;
                const int n = nBase + jh * 32 + jj * 16 + row16;
#pragma unroll
                for (int r = 0; r < 4; ++r) {
                    const int m = mBase + i * 16 + quad * 4 + r;
                    float e = 0.f;
                    if (n <= m)
                        e = __expf(acc[i][j][r] * 0.03125f - EXP_SHIFT);
                    rs[i][r] += e;
                    Ts[(i * 16 + quad * 4 + r) * 32 + jj * 16 + row16] = f2bf(e);
                }
            }
#pragma unroll
        for (int s = 0; s < 4; ++s) {
            const int row = s * 16 + (lane >> 2);
            int4 val = *(const int4*)(Ts + row * 32 + (lane & 3) * 8);
            *(int4*)(Sp + (size_t)(mBase + row) * 2048 +
                     nBase + jh * 32 + (lane & 3) * 8) = val;
        }
    }
#pragma unroll
    for (int i = 0; i < 4; ++i)
#pragma unroll
        for (int r = 0; r < 4; ++r) {
            float s = rs[i][r];
#pragma unroll
            for (int off = 1; off < 16; off <<= 1) s += __shfl_xor(s, off);
            if (row16 == 0)
                atomicAdd(srow_ptr((u16*)Sb, b, mBase + i * 16 + quad * 4 + r), s);
        }
}

// PV: O = (1/Srow) * P'.V; k-extent (mt+1)*128. grid 512 (1-D).
// Decode: nt = lin>>6 (D-chunk), g = lin&63 -> (mtp = g&15, b = g>>4).
// XCD-grouping: all 8 nt-blocks of a (mt,b) group share lin%8 == g%8 ->
// same XCD (assumes RR) -> P-tile read once from L3, 7x from L2.
// K-balance: mt = (b<2) ? 15-mtp : mtp, so blocks lin and lin+256 (same CU
// under RR wrap) have K-extents summing to a uniform 17*128.
__global__ __launch_bounds__(256, 4) void k_gemm_pv(u16* __restrict__ P,
                                                    const u16* __restrict__ Vt,
                                                    float* __restrict__ O) {
    __shared__ u16 smem[16384];
    const int lin = blockIdx.x;              // 0..511
    const int nt = lin >> 6;
    const int g = lin & 63;
    const int mtp = g & 15, b = g >> 4;
    const int mt = (b < 2) ? (15 - mtp) : mtp;
    const u16* Pp = P + (size_t)b * 2048 * 2048 + (size_t)mt * 128 * 2048;
    const u16* Vp = Vt + (size_t)b * 1024 * 2048 + (size_t)nt * 128 * 2048;
    f32x4 acc[4][4];
    gemm_core_nt(Pp, Vp, 2048, 2048, (mt + 1) * 128, smem, acc);
    float* Op = O + (size_t)b * 2048 * 1024;
    const int tid = threadIdx.x, wave = tid >> 6, lane = tid & 63;
    const int wm = (wave >> 1) * 64, wn = (wave & 1) * 64;
    const int row16 = lane & 15, quad = lane >> 4;
    float inv[4][4];
#pragma unroll
    for (int i = 0; i < 4; ++i)
#pragma unroll
        for (int r = 0; r < 4; ++r)
            inv[i][r] = 1.0f / *srow_ptr(P, b, mt * 128 + wm + i * 16 + quad * 4 + r);
#pragma unroll
    for (int i = 0; i < 4; ++i)
#pragma unroll
        for (int j = 0; j < 4; ++j) {
            int m = mt * 128 + wm + i * 16 + quad * 4;
            int n = nt * 128 + wn + j * 16 + row16;
#pragma unroll
            for (int r = 0; r < 4; ++r)
                Op[(size_t)(m + r) * 1024 + n] = acc[i][j][r] * inv[i][r];
        }
}

// ---------------- launcher ----------------
extern "C" void kernel_launch(void* const* d_in, const int* in_sizes, int n_in,
                              void* d_out, int out_size, void* d_ws, size_t ws_size,
                              hipStream_t stream) {
    const float* x  = (const float*)d_in[0];
    const float* Wq = (const float*)d_in[1];
    const float* Wk = (const float*)d_in[2];
    const float* Wv = (const float*)d_in[3];
    float* out = (float*)d_out;
    char* ws = (char*)d_ws;

    u16* xb  = (u16*)(ws);                          // 16 MB: x bf16 [8192,1024]
    u16* Wt3 = (u16*)(ws + (16u << 20));            //  6 MB
    u16* Qb  = (u16*)(ws + (22u << 20));            // 16 MB
    u16* Kb  = (u16*)(ws + (38u << 20));            // 16 MB
    u16* Vt  = (u16*)(ws + (54u << 20));            // 16 MB: V^T [B,1024,2048]
    u16* Sb  = (u16*)(ws + (70u << 20));            // 32 MB: P' (+Srow dead space)

    k_prep<<<7169, 256, 0, stream>>>(x, Wq, Wk, Wv, xb, Wt3, Sb);
    k_gemm_proj<<<dim3(24, 64), 256, 0, stream>>>(xb, Wt3, Qb, Kb, Vt);
    k_gemm_scores<<<544, 256, 0, stream>>>(Qb, Kb, Sb);
    k_gemm_pv<<<512, 256, 0, stream>>>(Sb, Vt, out);
}